// Round 7
// baseline (227.113 us; speedup 1.0000x reference)
//
#include <hip/hip_runtime.h>
#include <math.h>

typedef __attribute__((ext_vector_type(8))) short short8;
typedef __attribute__((ext_vector_type(4))) float float4v;

#define D_DIM 256
#define K_EMB 1024
#define HW_SZ 1024
#define N_TOT 32768
#define SMP_B (D_DIM * HW_SZ)  // per-batch stride in X (floats)

// ---- bf16 hi/lo split helpers (RNE) ----
__device__ __forceinline__ unsigned short f2bf(float x) {
  unsigned int u = __builtin_bit_cast(unsigned int, x);
  return (unsigned short)((u + 0x7fffu + ((u >> 16) & 1u)) >> 16);
}
__device__ __forceinline__ float bf2f(unsigned short h) {
  unsigned int u = ((unsigned int)h) << 16;
  return __builtin_bit_cast(float, u);
}

// ---------------------------------------------------------------- prep E ----
// block 0 also zeroes counts[1024] + lossX[64] + lossB[64] (stream-ordered
// before prep_x / epi atomics; replaces the hipMemsetAsync dispatch).
__global__ __launch_bounds__(256) void vq_prep_e(const float* __restrict__ E,
                                                 unsigned short* __restrict__ Ehi,
                                                 unsigned short* __restrict__ Elo,
                                                 float* __restrict__ enorm,
                                                 float* __restrict__ zbase) {
  const int t = threadIdx.x;
  if (blockIdx.x == 0) {
#pragma unroll
    for (int k = t; k < 1152; k += 256) zbase[k] = 0.f;
  }
  int tid = blockIdx.x * 256 + t;  // 32768 threads, 32 per code
  int c = tid >> 5;
  int d0 = (tid & 31) * 8;
  const float* p = E + c * D_DIM + d0;
  float s = 0.f;
  short8 hv, lv;
#pragma unroll
  for (int j = 0; j < 8; ++j) {
    float x = p[j];
    s = fmaf(x, x, s);
    unsigned short h = f2bf(x);
    hv[j] = (short)h;
    lv[j] = (short)f2bf(x - bf2f(h));
  }
  *(short8*)(Ehi + c * D_DIM + d0) = hv;
  *(short8*)(Elo + c * D_DIM + d0) = lv;
#pragma unroll
  for (int off = 1; off <= 16; off <<= 1) s += __shfl_xor(s, off);
  if ((tid & 31) == 0) enorm[c] = s;
}

// ---------------------------------------------------------------- prep X ----
// Transpose+convert X [b][d][hw] fp32 -> Xt_hi/Xt_lo [n=b*1024+hw][d] bf16.
// 64d x 64hw tile per block through LDS. Accumulates sum(x^2) for the loss:
// block-reduce -> ONE atomic per block, scattered over 64 slots (r4 lesson:
// 8192 same-address atomics serialized the whole grid, 112us).
__global__ __launch_bounds__(256) void vq_prep_x(const float* __restrict__ X,
                                                 unsigned short* __restrict__ Xh,
                                                 unsigned short* __restrict__ Xl,
                                                 float* __restrict__ lossX) {
  __shared__ float ts[64][65];  // +1 pad: 2-way-max banks on column reads
  __shared__ float xp[4];
  const int t = threadIdx.x;
  const int bi = blockIdx.x;
  const int b = bi >> 6;
  const int dt = (bi >> 4) & 3;
  const int ht = bi & 15;
  const int d0 = dt * 64;
  const int hw0 = ht * 64;

  {
    const int dl = t >> 4;
    const int hl = (t & 15) * 4;
#pragma unroll
    for (int i = 0; i < 4; ++i) {
      float4 v = *(const float4*)(X + b * SMP_B + (d0 + dl + i * 16) * HW_SZ + hw0 + hl);
      ts[dl + i * 16][hl + 0] = v.x;
      ts[dl + i * 16][hl + 1] = v.y;
      ts[dl + i * 16][hl + 2] = v.z;
      ts[dl + i * 16][hl + 3] = v.w;
    }
  }
  __syncthreads();
  float xsq = 0.f;
#pragma unroll
  for (int p = 0; p < 2; ++p) {
    const int c = t + p * 256;
    const int dch = c & 7;   // d chunk of 8
    const int nl = c >> 3;   // 0..63
    short8 hv, lv;
#pragma unroll
    for (int j = 0; j < 8; ++j) {
      float x = ts[dch * 8 + j][nl];
      xsq = fmaf(x, x, xsq);
      unsigned short h = f2bf(x);
      hv[j] = (short)h;
      lv[j] = (short)f2bf(x - bf2f(h));
    }
    const int n = b * 1024 + hw0 + nl;
    *(short8*)(Xh + n * D_DIM + d0 + dch * 8) = hv;
    *(short8*)(Xl + n * D_DIM + d0 + dch * 8) = lv;
  }
  // block reduce: wave partials -> LDS -> one scattered atomic per block
#pragma unroll
  for (int off = 1; off <= 32; off <<= 1) xsq += __shfl_xor(xsq, off);
  if ((t & 63) == 0) xp[t >> 6] = xsq;
  __syncthreads();
  if (t == 0) atomicAdd(&lossX[bi & 63], xp[0] + xp[1] + xp[2] + xp[3]);
}

// ------------------------------------------------------------------ gemm ----
// v7: NO-LDS gemm. r3/r5/r6 showed every LDS-staged schedule here pins
// MfmaUtil ~40%: the LDS pipe (staging writes + frag reads + barrier drains)
// is ~2x oversubscribed vs MFMA, and dbuf fixes cost the occupancy that hides
// it. But both operands are cache-resident (E hi+lo = 2MB total; X slices are
// XCD-L2-local under the block swizzle), and the MFMA fragment pattern is
// directly global-addressable: lane(l15,q) reads 16B at row*512B + dc*64 +
// q*16 -- the 4 q-groups of a wave cover whole 64B lines. So: load frags
// straight global->VGPR, zero LDS staging, ZERO barriers in the K-loop; the
// compiler software-pipelines the fully-unrolled loop freely (the thing every
// barriered structure could not do).
// VMEM demand ~402MB from L2 (~12-16us, pipe was 5% busy) vs MFMA floor
// ~25us -> MFMA-bound. Numerics: same bf16 values, same per-acc order
// (hh,hl,lh per dc) -> bit-identical to r6 (absmax 0.001941681).
// Block: 128 codes x 256 samples, 4 waves (wave-tile 64x128), 1024 blocks.
// LDS: 3KB argmin scratch only.
__global__ __launch_bounds__(256, 2) void vq_gemm(
    const unsigned short* __restrict__ Xh, const unsigned short* __restrict__ Xl,
    const unsigned short* __restrict__ Ehi, const unsigned short* __restrict__ Elo,
    const float* __restrict__ enorm, float* __restrict__ pval, int* __restrict__ pidx) {
  __shared__ float rv[2][256];
  __shared__ int ri[2][256];

  const int t = threadIdx.x;
  const int i = blockIdx.x;  // 0..1023
  // XCD-aware swizzle: the 8 code-stripes of one sample-block share i&7 -> same
  // XCD -> X frag re-reads are L2-local.
  const int cblk = (i >> 3) & 7;               // code stripe 0..7
  const int sblk = ((i >> 6) << 3) | (i & 7);  // sample block 0..127
  const int n0 = sblk * 256;

  const int lane = t & 63;
  const int wv = t >> 6;
  const int wm = wv >> 1;  // code half (0..1)
  const int wn = wv & 1;   // sample half (0..1), 128 samples each
  const int l15 = lane & 15;
  const int q = lane >> 4;

  float4v acc[4][8];
#pragma unroll
  for (int a = 0; a < 4; ++a)
#pragma unroll
    for (int c = 0; c < 8; ++c) acc[a][c] = {0.f, 0.f, 0.f, 0.f};

  // per-lane fragment base pointers (A: codes, B: samples), both [row][d] bf16
  const unsigned short* eh0 = Ehi + (cblk * 128 + wm * 64 + l15) * D_DIM + q * 8;
  const unsigned short* el0 = Elo + (cblk * 128 + wm * 64 + l15) * D_DIM + q * 8;
  const unsigned short* xh0 = Xh + (n0 + wn * 128 + l15) * D_DIM + q * 8;
  const unsigned short* xl0 = Xl + (n0 + wn * 128 + l15) * D_DIM + q * 8;

#pragma unroll
  for (int dc = 0; dc < 8; ++dc) {
    const int d0 = dc * 32;
    short8 ah[4], al[4];
#pragma unroll
    for (int mi = 0; mi < 4; ++mi) {
      ah[mi] = *(const short8*)(eh0 + mi * 16 * D_DIM + d0);
      al[mi] = *(const short8*)(el0 + mi * 16 * D_DIM + d0);
    }
    // two ni-halves of 4 to bound live X-frag registers (acc128 + E32 + X32)
#pragma unroll
    for (int h = 0; h < 2; ++h) {
      short8 xh[4], xl[4];
#pragma unroll
      for (int nj = 0; nj < 4; ++nj) {
        xh[nj] = *(const short8*)(xh0 + (h * 4 + nj) * 16 * D_DIM + d0);
        xl[nj] = *(const short8*)(xl0 + (h * 4 + nj) * 16 * D_DIM + d0);
      }
      // per-acc order identical to r6: +ah.xh, +ah.xl, +al.xh
#pragma unroll
      for (int mi = 0; mi < 4; ++mi)
#pragma unroll
        for (int nj = 0; nj < 4; ++nj)
          acc[mi][h * 4 + nj] =
              __builtin_amdgcn_mfma_f32_16x16x32_bf16(ah[mi], xh[nj], acc[mi][h * 4 + nj], 0, 0, 0);
#pragma unroll
      for (int mi = 0; mi < 4; ++mi)
#pragma unroll
        for (int nj = 0; nj < 4; ++nj)
          acc[mi][h * 4 + nj] =
              __builtin_amdgcn_mfma_f32_16x16x32_bf16(ah[mi], xl[nj], acc[mi][h * 4 + nj], 0, 0, 0);
#pragma unroll
      for (int mi = 0; mi < 4; ++mi)
#pragma unroll
        for (int nj = 0; nj < 4; ++nj)
          acc[mi][h * 4 + nj] =
              __builtin_amdgcn_mfma_f32_16x16x32_bf16(al[mi], xh[nj], acc[mi][h * 4 + nj], 0, 0, 0);
    }
  }

  // ---- per-sample argmin over this block's 128 codes ----
  float en[16];
#pragma unroll
  for (int mi = 0; mi < 4; ++mi)
#pragma unroll
    for (int r = 0; r < 4; ++r)
      en[mi * 4 + r] = enorm[cblk * 128 + wm * 64 + mi * 16 + q * 4 + r];

#pragma unroll
  for (int ni = 0; ni < 8; ++ni) {
    float bv = 1e30f;
    int bc = 0;
#pragma unroll
    for (int mi = 0; mi < 4; ++mi)
#pragma unroll
      for (int r = 0; r < 4; ++r) {
        float v = fmaf(-2.f, acc[mi][ni][r], en[mi * 4 + r]);
        if (v < bv) { bv = v; bc = wm * 64 + mi * 16 + q * 4 + r; }  // ascending c
      }
#pragma unroll
    for (int off = 16; off <= 32; off <<= 1) {  // merge the 4 q-groups
      float ov = __shfl_xor(bv, off);
      int oc = __shfl_xor(bc, off);
      if (ov < bv || (ov == bv && oc < bc)) { bv = ov; bc = oc; }
    }
    if (q == 0) {
      rv[wm][wn * 128 + ni * 16 + l15] = bv;
      ri[wm][wn * 128 + ni * 16 + l15] = cblk * 128 + bc;
    }
  }
  __syncthreads();
  if (t < 256) {  // merge code halves (wm0 codes < wm1 codes: tie keeps wm0)
    float v0 = rv[0][t];
    int c0 = ri[0][t];
    float v1 = rv[1][t];
    int c1 = ri[1][t];
    if (v1 < v0) { v0 = v1; c0 = c1; }
    pval[cblk * N_TOT + sblk * 256 + t] = v0;
    pidx[cblk * N_TOT + sblk * 256 + t] = c0;
  }
}

// -------------------------------------------------------------- epilogue ----
// No X read: loss = sum||x||^2 (prep_x) + sum(bv); bv = enorm[best] - 2*S_best
// is exactly the merged argmin value. Sum(bv) scattered over 64 slots.
__global__ __launch_bounds__(256) void vq_epi(
    const float* __restrict__ E,
    const float* __restrict__ pval, const int* __restrict__ pidx,
    float* __restrict__ out, float* __restrict__ counts,
    float* __restrict__ lossB) {
  __shared__ int best_idx[64];
  __shared__ float es[64][257];  // gathered best-code rows, fp32
  const int t = threadIdx.x;
  const int n0 = blockIdx.x * 64;
  const int b = n0 >> 10;
  const int hw0 = n0 & 1023;

  if (t < 64) {  // wave 0: stripe merge + counts + sum(bv)
    int n = n0 + t;
    float bv = 1e30f;
    int bc = 0;
#pragma unroll
    for (int s = 0; s < 8; ++s) {  // ascending stripe = ascending code range
      float v = pval[s * N_TOT + n];
      int c = pidx[s * N_TOT + n];
      if (v < bv || (v == bv && c < bc)) { bv = v; bc = c; }
    }
    best_idx[t] = bc;
    atomicAdd(&counts[bc], 1.0f);
    float s = bv;
#pragma unroll
    for (int off = 1; off <= 32; off <<= 1) s += __shfl_xor(s, off);
    if (t == 0) atomicAdd(&lossB[blockIdx.x & 63], s);  // 8 blocks/slot
  }
  __syncthreads();

  // gather the 64 best-code E rows into LDS (coalesced 1KB/wave global reads)
#pragma unroll
  for (int i = 0; i < 16; ++i) {
    const int c = t + i * 256;
    const int r = c >> 6;           // wave-uniform row
    const int col = (c & 63) * 4;
    float4 v = *(const float4*)(E + best_idx[r] * D_DIM + col);
    es[r][col + 0] = v.x;
    es[r][col + 1] = v.y;
    es[r][col + 2] = v.z;
    es[r][col + 3] = v.w;
  }
  __syncthreads();

  const int nl4 = (t & 15) * 4;
  const int drow = t >> 4;
  float* Op = out + b * SMP_B + hw0 + nl4;
#pragma unroll 4
  for (int d = drow; d < D_DIM; d += 16) {
    float4 qv;
    qv.x = es[nl4 + 0][d];
    qv.y = es[nl4 + 1][d];
    qv.z = es[nl4 + 2][d];
    qv.w = es[nl4 + 3][d];
    *(float4*)(Op + d * HW_SZ) = qv;
  }
}

// -------------------------------------------------------------- finalize ----
// lossv = lossX[64] ++ lossB[64] contiguous: sum(x^2) and sum(bv) partials.
__global__ __launch_bounds__(256) void vq_finalize(const float* __restrict__ counts,
                                                   const float* __restrict__ lossv,
                                                   float* __restrict__ out_tail) {
  __shared__ float part[4];
  __shared__ float lpart[4];
  const int t = threadIdx.x;
  float s = 0.f;
#pragma unroll
  for (int k = t; k < K_EMB; k += 256) {
    float p = counts[k] * (1.0f / 32768.0f);
    s = fmaf(p, logf(p + 1e-10f), s);
  }
  float l = (t < 128) ? lossv[t] : 0.f;
#pragma unroll
  for (int off = 32; off >= 1; off >>= 1) {
    s += __shfl_xor(s, off);
    l += __shfl_xor(l, off);
  }
  if ((t & 63) == 0) { part[t >> 6] = s; lpart[t >> 6] = l; }
  __syncthreads();
  if (t == 0) {
    float tot = part[0] + part[1] + part[2] + part[3];
    float L = lpart[0] + lpart[1] + lpart[2] + lpart[3];
    // sum(q-x)^2 = sum||x||^2 + sum(bv); separate slot groups so small bv
    // increments aren't rounded away against the ~8.4e6 x^2 accumulators
    out_tail[0] = 1.25f * L * (1.0f / 8388608.0f);
    out_tail[1] = expf(-tot);
  }
}

// ---------------------------------------------------------------- launch ----
extern "C" void kernel_launch(void* const* d_in, const int* in_sizes, int n_in,
                              void* d_out, int out_size, void* d_ws, size_t ws_size,
                              hipStream_t stream) {
  const float* X = (const float*)d_in[0];  // [32,256,32,32]
  const float* E = (const float*)d_in[1];  // [1024,256]
  float* out = (float*)d_out;              // 8388608 + 2
  float* ws = (float*)d_ws;

  // d_out doubles as scratch for transposed bf16 X (exactly 8388608 floats);
  // vq_epi fully overwrites it afterwards with the real output.
  unsigned short* Xh = (unsigned short*)out;      // [32768][256] bf16
  unsigned short* Xl = Xh + N_TOT * D_DIM;        // [32768][256] bf16

  unsigned short* Ehi = (unsigned short*)ws;  // 262144 bf16 = 131072 floats
  unsigned short* Elo = Ehi + 262144;
  float* enorm = ws + 262144;                 // [1024]
  float* counts = ws + 263168;                // [1024]
  float* lossX = ws + 264192;                 // [64] sum(x^2) partials
  float* lossB = ws + 264256;                 // [64] sum(bv) partials
  float* pval = ws + 264320;                  // [8*32768]
  int* pidx = (int*)(ws + 264320 + 262144);   // [8*32768]

  vq_prep_e<<<128, 256, 0, stream>>>(E, Ehi, Elo, enorm, counts);  // +zeroing
  vq_prep_x<<<2048, 256, 0, stream>>>(X, Xh, Xl, lossX);
  vq_gemm<<<1024, 256, 0, stream>>>(Xh, Xl, Ehi, Elo, enorm, pval, pidx);
  vq_epi<<<512, 256, 0, stream>>>(E, pval, pidx, out, counts, lossB);
  vq_finalize<<<1, 256, 0, stream>>>(counts, lossX, out + 8388608);
}

// Round 8
// 161.753 us; speedup vs baseline: 1.4041x; 1.4041x over previous
//
#include <hip/hip_runtime.h>
#include <math.h>

typedef __attribute__((ext_vector_type(8))) short short8;
typedef __attribute__((ext_vector_type(4))) float float4v;

#define D_DIM 256
#define K_EMB 1024
#define HW_SZ 1024
#define N_TOT 32768
#define SMP_B (D_DIM * HW_SZ)  // per-batch stride in X (floats)

// ---- bf16 hi/lo split helpers (RNE) ----
__device__ __forceinline__ unsigned short f2bf(float x) {
  unsigned int u = __builtin_bit_cast(unsigned int, x);
  return (unsigned short)((u + 0x7fffu + ((u >> 16) & 1u)) >> 16);
}
__device__ __forceinline__ float bf2f(unsigned short h) {
  unsigned int u = ((unsigned int)h) << 16;
  return __builtin_bit_cast(float, u);
}

// ---- async global->LDS, 16B/lane (dest = wave-uniform base + lane*16) ----
typedef const __attribute__((address_space(1))) void GV;
typedef __attribute__((address_space(3))) void LV;
__device__ __forceinline__ void async16(const void* g, void* l) {
  __builtin_amdgcn_global_load_lds((GV*)g, (LV*)l, 16, 0, 0);
}

// ------------------------------------------------------------ fused prep ----
// blocks [0,2048): transpose+convert X -> Xh/Xl; per-block sum(x^2) DIRECT
// store to lossX[bi] (no atomics -> no zero-ordering race within dispatch).
// blocks [2048,2176): convert E -> Ehi/Elo + enorm; block 2048 zeroes
// counts[1024] only (consumed by vq_epi, next-next dispatch: ordered).
__global__ __launch_bounds__(256) void vq_prep(
    const float* __restrict__ X, const float* __restrict__ E,
    unsigned short* __restrict__ Xh, unsigned short* __restrict__ Xl,
    unsigned short* __restrict__ Ehi, unsigned short* __restrict__ Elo,
    float* __restrict__ enorm, float* __restrict__ counts,
    float* __restrict__ lossX) {
  __shared__ float ts[64][65];  // +1 pad: 2-way-max banks on column reads
  __shared__ float xp[4];
  const int t = threadIdx.x;
  const int bi = blockIdx.x;

  if (bi >= 2048) {  // ---- prep E ----
    const int pe = bi - 2048;
    if (pe == 0) {
#pragma unroll
      for (int k = t; k < K_EMB; k += 256) counts[k] = 0.f;
    }
    int tid = pe * 256 + t;  // 32768 threads, 32 per code
    int c = tid >> 5;
    int d0 = (tid & 31) * 8;
    const float* p = E + c * D_DIM + d0;
    float s = 0.f;
    short8 hv, lv;
#pragma unroll
    for (int j = 0; j < 8; ++j) {
      float x = p[j];
      s = fmaf(x, x, s);
      unsigned short h = f2bf(x);
      hv[j] = (short)h;
      lv[j] = (short)f2bf(x - bf2f(h));
    }
    *(short8*)(Ehi + c * D_DIM + d0) = hv;
    *(short8*)(Elo + c * D_DIM + d0) = lv;
#pragma unroll
    for (int off = 1; off <= 16; off <<= 1) s += __shfl_xor(s, off);
    if ((tid & 31) == 0) enorm[c] = s;
    return;
  }

  // ---- prep X: 64d x 64hw tile per block through LDS ----
  const int b = bi >> 6;
  const int dt = (bi >> 4) & 3;
  const int ht = bi & 15;
  const int d0 = dt * 64;
  const int hw0 = ht * 64;
  {
    const int dl = t >> 4;
    const int hl = (t & 15) * 4;
#pragma unroll
    for (int i = 0; i < 4; ++i) {
      float4 v = *(const float4*)(X + b * SMP_B + (d0 + dl + i * 16) * HW_SZ + hw0 + hl);
      ts[dl + i * 16][hl + 0] = v.x;
      ts[dl + i * 16][hl + 1] = v.y;
      ts[dl + i * 16][hl + 2] = v.z;
      ts[dl + i * 16][hl + 3] = v.w;
    }
  }
  __syncthreads();
  float xsq = 0.f;
#pragma unroll
  for (int p = 0; p < 2; ++p) {
    const int c = t + p * 256;
    const int dch = c & 7;   // d chunk of 8
    const int nl = c >> 3;   // 0..63
    short8 hv, lv;
#pragma unroll
    for (int j = 0; j < 8; ++j) {
      float x = ts[dch * 8 + j][nl];
      xsq = fmaf(x, x, xsq);
      unsigned short h = f2bf(x);
      hv[j] = (short)h;
      lv[j] = (short)f2bf(x - bf2f(h));
    }
    const int n = b * 1024 + hw0 + nl;
    *(short8*)(Xh + n * D_DIM + d0 + dch * 8) = hv;
    *(short8*)(Xl + n * D_DIM + d0 + dch * 8) = lv;
  }
  // block reduce sum(x^2) -> direct per-block slot (no atomic, no contention)
#pragma unroll
  for (int off = 1; off <= 32; off <<= 1) xsq += __shfl_xor(xsq, off);
  if ((t & 63) == 0) xp[t >> 6] = xsq;
  __syncthreads();
  if (t == 0) lossX[bi] = xp[0] + xp[1] + xp[2] + xp[3];
}

// ------------------------------------------------------------------ gemm ----
// r6 verbatim (best measured: 51.2us, MfmaUtil ~40, conflicts 0).
// Block = 128 codes x 256 samples, 4 waves (wave-tile 64x128), 1024 blocks.
// 2-phase single-buffer loop; T2 chunk swizzle; XCD block swizzle.
// The structure is LDS-pipe bound (operand reads amplified 2x by wm/wn
// reuse); 3 restructures (dbuf 8-wave, no-LDS, 3-phase) all regressed --
// do not perturb without the full 8-phase derived-wait port.
// Numerics frozen: 3-term split is load-bearing for the PERPLEXITY check
// (argmin flips shift code counts; even ~100 flips moves perplexity past
// the absmax fingerprint). Accumulation order per acc element must stay:
// +ah.xh, +ah.xl, +al.xh per dc ascending.
__global__ __launch_bounds__(256, 2) void vq_gemm(
    const unsigned short* __restrict__ Xh, const unsigned short* __restrict__ Xl,
    const unsigned short* __restrict__ Ehi, const unsigned short* __restrict__ Elo,
    const float* __restrict__ enorm, float* __restrict__ pval, int* __restrict__ pidx) {
  __shared__ unsigned short es_hi[128 * 32];  // 8 KB [code][d-chunk swizzled]
  __shared__ unsigned short es_lo[128 * 32];
  __shared__ unsigned short xs_hi[256 * 32];  // 16 KB [smp][d-chunk swizzled]
  __shared__ unsigned short xs_lo[256 * 32];
  __shared__ float rv[2][256];
  __shared__ int ri[2][256];

  const int t = threadIdx.x;
  const int i = blockIdx.x;  // 0..1023
  // XCD-aware swizzle: all 8 code-stripes of one sample-block share i&7 -> same XCD
  const int cblk = (i >> 3) & 7;               // code stripe 0..7
  const int sblk = ((i >> 6) << 3) | (i & 7);  // sample block 0..127
  const int n0 = sblk * 256;

  const int lane = t & 63;
  const int wv = t >> 6;
  const int wm = wv >> 1;  // code half (0..1)
  const int wn = wv & 1;   // sample half (0..1), 128 samples each
  const int l15 = lane & 15;
  const int q = lane >> 4;

  float4v acc[4][8];
#pragma unroll
  for (int a = 0; a < 4; ++a)
#pragma unroll
    for (int c = 0; c < 8; ++c) acc[a][c] = {0.f, 0.f, 0.f, 0.f};

  const int srow = t >> 2;  // 0..63 (row within 64-row staging group)
  // T2 chunk swizzle: LDS slot (t&3) of row r holds data chunk (t&3)^((r>>1)&3).
  // global_load_lds dest stays LINEAR; global source column inverse-permuted
  // per lane. Row offsets of 64 preserve the XOR pattern (64/2 % 4 == 0).
  const int scol = (((t & 3) ^ ((t >> 3) & 3)) << 3);
  const unsigned short* xhb = Xh + (n0 + srow) * D_DIM + scol;
  const unsigned short* xlb = Xl + (n0 + srow) * D_DIM + scol;
  const unsigned short* ehb = Ehi + (cblk * 128 + srow) * D_DIM + scol;
  const unsigned short* elb = Elo + (cblk * 128 + srow) * D_DIM + scol;
  char* xh_b = (char*)xs_hi;
  char* xl_b = (char*)xs_lo;
  char* eh_b = (char*)es_hi;
  char* el_b = (char*)es_lo;
  const int dst0 = t * 16;

  // fragment-read column after swizzle: row = base16k + l15 -> (row>>1)&3 = (l15>>1)&3
  const int fcol = (q ^ ((l15 >> 1) & 3)) * 8;

  for (int dc = 0; dc < 8; ++dc) {
    const int d0 = dc * 32;
    // E tiles: 128 rows each (8KB, 2 calls)
    async16(ehb + d0, eh_b + dst0);
    async16(ehb + 64 * D_DIM + d0, eh_b + dst0 + 4096);
    async16(elb + d0, el_b + dst0);
    async16(elb + 64 * D_DIM + d0, el_b + dst0 + 4096);
    // X tiles: 256 rows each (16KB, 4 calls)
    async16(xhb + d0, xh_b + dst0);
    async16(xhb + 64 * D_DIM + d0, xh_b + dst0 + 4096);
    async16(xhb + 128 * D_DIM + d0, xh_b + dst0 + 8192);
    async16(xhb + 192 * D_DIM + d0, xh_b + dst0 + 12288);
    async16(xlb + d0, xl_b + dst0);
    async16(xlb + 64 * D_DIM + d0, xl_b + dst0 + 4096);
    async16(xlb + 128 * D_DIM + d0, xl_b + dst0 + 8192);
    async16(xlb + 192 * D_DIM + d0, xl_b + dst0 + 12288);
    __syncthreads();  // barrier drains vmcnt -> tiles visible

    short8 ah[4], al[4], xh[8], xl[8];
#pragma unroll
    for (int mi = 0; mi < 4; ++mi) {
      int row = wm * 64 + mi * 16 + l15;
      ah[mi] = *(const short8*)&es_hi[row * 32 + fcol];
      al[mi] = *(const short8*)&es_lo[row * 32 + fcol];
    }
#pragma unroll
    for (int ni = 0; ni < 8; ++ni) {
      int row = wn * 128 + ni * 16 + l15;
      xh[ni] = *(const short8*)&xs_hi[row * 32 + fcol];
      xl[ni] = *(const short8*)&xs_lo[row * 32 + fcol];
    }
#pragma unroll
    for (int mi = 0; mi < 4; ++mi)
#pragma unroll
      for (int ni = 0; ni < 8; ++ni)
        acc[mi][ni] = __builtin_amdgcn_mfma_f32_16x16x32_bf16(ah[mi], xh[ni], acc[mi][ni], 0, 0, 0);
#pragma unroll
    for (int mi = 0; mi < 4; ++mi)
#pragma unroll
      for (int ni = 0; ni < 8; ++ni)
        acc[mi][ni] = __builtin_amdgcn_mfma_f32_16x16x32_bf16(ah[mi], xl[ni], acc[mi][ni], 0, 0, 0);
#pragma unroll
    for (int mi = 0; mi < 4; ++mi)
#pragma unroll
      for (int ni = 0; ni < 8; ++ni)
        acc[mi][ni] = __builtin_amdgcn_mfma_f32_16x16x32_bf16(al[mi], xh[ni], acc[mi][ni], 0, 0, 0);
    __syncthreads();  // all frag reads done before next stage overwrites
  }

  // ---- per-sample argmin over this block's 128 codes ----
  float en[16];
#pragma unroll
  for (int mi = 0; mi < 4; ++mi)
#pragma unroll
    for (int r = 0; r < 4; ++r)
      en[mi * 4 + r] = enorm[cblk * 128 + wm * 64 + mi * 16 + q * 4 + r];

#pragma unroll
  for (int ni = 0; ni < 8; ++ni) {
    float bv = 1e30f;
    int bc = 0;
#pragma unroll
    for (int mi = 0; mi < 4; ++mi)
#pragma unroll
      for (int r = 0; r < 4; ++r) {
        float v = fmaf(-2.f, acc[mi][ni][r], en[mi * 4 + r]);
        if (v < bv) { bv = v; bc = wm * 64 + mi * 16 + q * 4 + r; }  // ascending c
      }
#pragma unroll
    for (int off = 16; off <= 32; off <<= 1) {  // merge the 4 q-groups
      float ov = __shfl_xor(bv, off);
      int oc = __shfl_xor(bc, off);
      if (ov < bv || (ov == bv && oc < bc)) { bv = ov; bc = oc; }
    }
    if (q == 0) {
      rv[wm][wn * 128 + ni * 16 + l15] = bv;
      ri[wm][wn * 128 + ni * 16 + l15] = cblk * 128 + bc;
    }
  }
  __syncthreads();
  if (t < 256) {  // merge code halves (wm0 codes < wm1 codes: tie keeps wm0)
    float v0 = rv[0][t];
    int c0 = ri[0][t];
    float v1 = rv[1][t];
    int c1 = ri[1][t];
    if (v1 < v0) { v0 = v1; c0 = c1; }
    pval[cblk * N_TOT + sblk * 256 + t] = v0;
    pidx[cblk * N_TOT + sblk * 256 + t] = c0;
  }
}

// -------------------------------------------------------------- epilogue ----
// No X read: loss = sum||x||^2 (prep) + sum(bv); bv = enorm[best] - 2*S_best
// is exactly the merged argmin value. Per-block direct store (no atomic).
__global__ __launch_bounds__(256) void vq_epi(
    const float* __restrict__ E,
    const float* __restrict__ pval, const int* __restrict__ pidx,
    float* __restrict__ out, float* __restrict__ counts,
    float* __restrict__ lossB) {
  __shared__ int best_idx[64];
  __shared__ float es[64][257];  // gathered best-code rows, fp32
  const int t = threadIdx.x;
  const int n0 = blockIdx.x * 64;
  const int b = n0 >> 10;
  const int hw0 = n0 & 1023;

  if (t < 64) {  // wave 0: stripe merge + counts + sum(bv)
    int n = n0 + t;
    float bv = 1e30f;
    int bc = 0;
#pragma unroll
    for (int s = 0; s < 8; ++s) {  // ascending stripe = ascending code range
      float v = pval[s * N_TOT + n];
      int c = pidx[s * N_TOT + n];
      if (v < bv || (v == bv && c < bc)) { bv = v; bc = c; }
    }
    best_idx[t] = bc;
    atomicAdd(&counts[bc], 1.0f);
    float s = bv;
#pragma unroll
    for (int off = 1; off <= 32; off <<= 1) s += __shfl_xor(s, off);
    if (t == 0) lossB[blockIdx.x] = s;  // direct store, no contention
  }
  __syncthreads();

  // gather the 64 best-code E rows into LDS (coalesced 1KB/wave global reads)
#pragma unroll
  for (int i = 0; i < 16; ++i) {
    const int c = t + i * 256;
    const int r = c >> 6;           // wave-uniform row
    const int col = (c & 63) * 4;
    float4 v = *(const float4*)(E + best_idx[r] * D_DIM + col);
    es[r][col + 0] = v.x;
    es[r][col + 1] = v.y;
    es[r][col + 2] = v.z;
    es[r][col + 3] = v.w;
  }
  __syncthreads();

  const int nl4 = (t & 15) * 4;
  const int drow = t >> 4;
  float* Op = out + b * SMP_B + hw0 + nl4;
#pragma unroll 4
  for (int d = drow; d < D_DIM; d += 16) {
    float4 qv;
    qv.x = es[nl4 + 0][d];
    qv.y = es[nl4 + 1][d];
    qv.z = es[nl4 + 2][d];
    qv.w = es[nl4 + 3][d];
    *(float4*)(Op + d * HW_SZ) = qv;
  }
}

// -------------------------------------------------------------- finalize ----
// Reduces counts[1024] (entropy), lossX[2048] + lossB[512] (loss partials).
__global__ __launch_bounds__(256) void vq_finalize(const float* __restrict__ counts,
                                                   const float* __restrict__ lossX,
                                                   const float* __restrict__ lossB,
                                                   float* __restrict__ out_tail) {
  __shared__ float part[4];
  __shared__ float lpart[4];
  const int t = threadIdx.x;
  float s = 0.f;
#pragma unroll
  for (int k = t; k < K_EMB; k += 256) {
    float p = counts[k] * (1.0f / 32768.0f);
    s = fmaf(p, logf(p + 1e-10f), s);
  }
  float l = 0.f;
#pragma unroll
  for (int k = t; k < 2048; k += 256) l += lossX[k];  // sum(x^2) partials
#pragma unroll
  for (int k = t; k < 512; k += 256) l += lossB[k];   // sum(bv) partials
#pragma unroll
  for (int off = 32; off >= 1; off >>= 1) {
    s += __shfl_xor(s, off);
    l += __shfl_xor(l, off);
  }
  if ((t & 63) == 0) { part[t >> 6] = s; lpart[t >> 6] = l; }
  __syncthreads();
  if (t == 0) {
    float tot = part[0] + part[1] + part[2] + part[3];
    float L = lpart[0] + lpart[1] + lpart[2] + lpart[3];
    // sum(q-x)^2 = sum||x||^2 + sum(bv); partials kept separate so small bv
    // terms aren't rounded away against the ~8.4e6 x^2 totals
    out_tail[0] = 1.25f * L * (1.0f / 8388608.0f);
    out_tail[1] = expf(-tot);
  }
}

// ---------------------------------------------------------------- launch ----
extern "C" void kernel_launch(void* const* d_in, const int* in_sizes, int n_in,
                              void* d_out, int out_size, void* d_ws, size_t ws_size,
                              hipStream_t stream) {
  const float* X = (const float*)d_in[0];  // [32,256,32,32]
  const float* E = (const float*)d_in[1];  // [1024,256]
  float* out = (float*)d_out;              // 8388608 + 2
  float* ws = (float*)d_ws;

  // d_out doubles as scratch for transposed bf16 X (exactly 8388608 floats);
  // vq_epi fully overwrites it afterwards with the real output.
  unsigned short* Xh = (unsigned short*)out;      // [32768][256] bf16
  unsigned short* Xl = Xh + N_TOT * D_DIM;        // [32768][256] bf16

  unsigned short* Ehi = (unsigned short*)ws;  // 262144 bf16 = 131072 floats
  unsigned short* Elo = Ehi + 262144;
  float* enorm = ws + 262144;                 // [1024]
  float* counts = ws + 263168;                // [1024]
  float* lossX = ws + 264192;                 // [2048] per-block sum(x^2)
  float* lossB = ws + 266240;                 // [512]  per-block sum(bv)
  float* pval = ws + 266752;                  // [8*32768]
  int* pidx = (int*)(ws + 266752 + 262144);   // [8*32768]

  vq_prep<<<2176, 256, 0, stream>>>(X, E, Xh, Xl, Ehi, Elo, enorm, counts, lossX);
  vq_gemm<<<1024, 256, 0, stream>>>(Xh, Xl, Ehi, Elo, enorm, pval, pidx);
  vq_epi<<<512, 256, 0, stream>>>(E, pval, pidx, out, counts, lossB);
  vq_finalize<<<1, 256, 0, stream>>>(counts, lossX, lossB, out + 8388608);
}